// Round 7
// baseline (174.729 us; speedup 1.0000x reference)
//
#include <hip/hip_runtime.h>
#include <math.h>

#define Bb 16
#define Nn 1024
#define Dd 16
#define NL 15

typedef __attribute__((ext_vector_type(8))) short short8;
typedef __attribute__((ext_vector_type(16))) float f32x16;
typedef __attribute__((ext_vector_type(4))) unsigned uint4v;

#if __has_builtin(__builtin_amdgcn_exp2f)
#define EXP2(x) __builtin_amdgcn_exp2f(x)
#else
#define EXP2(x) exp2f(x)
#endif

// LDS layout (dynamic, 68224 B; x2 blocks/CU = 136448 <= 160K):
//   K   : [1024 keys][16 shorts]          offset 0      32768 B
//   V^T : [16 d][VSTR=1044 shorts]        offset 32768  33408 B
//   O   : [512 q][16 f32]                 offset 0      32768 B (overlays K
//         after the attention loop; barriers guard both ends)
//   rs  : [512 f32]                       offset 66176   2048 B
#define VSTR 1044
#define V_OFF 32768
#define RS_OFF 66176
#define LDS_TOTAL 68224

__device__ __forceinline__ unsigned pack2bf(float a, float b) {
    unsigned ua = __float_as_uint(a) + 0x8000u;
    unsigned ub = __float_as_uint(b) + 0x8000u;
    return (ua >> 16) | (ub & 0xffff0000u);
}
__device__ __forceinline__ unsigned short bf1(float a) {
    return (unsigned short)((__float_as_uint(a) + 0x8000u) >> 16);
}

__device__ __forceinline__ void project(const float* __restrict__ xrow,
                                        const float* __restrict__ W,
                                        const float* __restrict__ bias,
                                        int i, float* __restrict__ q) {
#pragma unroll
    for (int r = 0; r < 16; r++) q[r] = 0.f;
    for (int c = 0; c < i; c++) {
        float xc = xrow[c];
#pragma unroll
        for (int r = 0; r < 16; r++) q[r] = fmaf(xc, W[r * 16 + c], q[r]);
    }
#pragma unroll
    for (int r = 0; r < 16; r++) q[r] = (r < i) ? (q[r] + bias[r]) : 0.f;
}

__device__ __forceinline__ void load_row16(const float* __restrict__ p, float* __restrict__ x) {
    const float4* xp = (const float4*)p;
    float4 a = xp[0], b = xp[1], c = xp[2], d = xp[3];
    x[0]=a.x; x[1]=a.y; x[2]=a.z; x[3]=a.w;
    x[4]=b.x; x[5]=b.y; x[6]=b.z; x[7]=b.w;
    x[8]=c.x; x[9]=c.y; x[10]=c.z; x[11]=c.w;
    x[12]=d.x; x[13]=d.y; x[14]=d.z; x[15]=d.w;
}

// ---------------------------------------------------------------------------
// Fused flash attention, all-32x32x16 MFMA, query-split (2 blocks per (l,b)).
// grid (NL, Bb, 2): block z=s covers queries s*512..+511; 1024 threads
// (16 waves x 32 queries each). Each block stages all 1024 K/V rows.
// QK C-frag (exp'd+packed) reused bit-identically as PV A-frag (R5-verified).
// launch_bounds (1024,4): R5's proven compile regime; actual VGPR count
// (expect <=64) determines whether HW runs 2 blocks/CU.
// ---------------------------------------------------------------------------
__launch_bounds__(1024, 4)
__global__ void gf_fused(const float* __restrict__ X,
                         const float* __restrict__ Wq, const float* __restrict__ bq,
                         const float* __restrict__ Wk, const float* __restrict__ bk,
                         const float* __restrict__ Wv, const float* __restrict__ bv,
                         const float* __restrict__ Wo, const float* __restrict__ bo,
                         const float* __restrict__ Wf, const float* __restrict__ bf,
                         float* __restrict__ als, float* __restrict__ out) {
    extern __shared__ char smem[];
    const int l = blockIdx.x, b = blockIdx.y, s = blockIdx.z, i = l + 1;
    const int t = threadIdx.x;
    const int wid = t >> 6, lane = t & 63;
    const int q31 = lane & 31, h = lane >> 5;
    const int qbase = s * 512;
    const float qscale = 1.4426950408889634f * rsqrtf((float)i);

    unsigned short* Ksh = (unsigned short*)smem;
    unsigned short* Vsh = (unsigned short*)(smem + V_OFF);

    const float* Xb  = X  + (size_t)b * Nn * Dd;
    const float* wq  = Wq + l * 256;  const float* bql = bq + l * 16;
    const float* wk  = Wk + l * 256;  const float* bkl = bk + l * 16;
    const float* wvp = Wv + l * 256;  const float* bvl = bv + l * 16;
    const float* wo  = Wo + l * 256;  const float* bol = bo + l * 16;
    const float* wf  = Wf + l * 32;   const float* bfl = bf + l * 2;

    // ---- proj phase: thread t stages K/V row t; Q for its wave's query ----
    unsigned qu[8];                 // Q row (qbase + wid*32 + q31), bf16 pairs
    {
        float xr[16]; load_row16(Xb + (size_t)t * Dd, xr);
        float tmp[16];
        unsigned u[8];

        project(xr, wk, bkl, i, tmp);
#pragma unroll
        for (int r = 0; r < 8; r++) u[r] = pack2bf(tmp[2*r], tmp[2*r+1]);
        {
            uint4* kd = (uint4*)(Ksh + t * 16);
            kd[0] = make_uint4(u[0], u[1], u[2], u[3]);
            kd[1] = make_uint4(u[4], u[5], u[6], u[7]);
        }

        project(xr, wvp, bvl, i, tmp);
#pragma unroll
        for (int d = 0; d < 16; d++) Vsh[d * VSTR + t] = bf1(tmp[d]);

        const int qrow = qbase + wid * 32 + q31;     // lanes 32-63 duplicate 0-31
        float xq[16]; load_row16(Xb + (size_t)qrow * Dd, xq);
        project(xq, wq, bql, i, tmp);
#pragma unroll
        for (int r = 0; r < 8; r++) qu[r] = pack2bf(tmp[2*r] * qscale, tmp[2*r+1] * qscale);
    }
    __syncthreads();

    // ---- Q B-frag via same-wave shuffles ----
    short8 qf;
    {
        unsigned d0[4];
#pragma unroll
        for (int j = 0; j < 4; j++) {
            unsigned lo = __shfl(qu[j], q31);
            unsigned hi = __shfl(qu[4 + j], q31);
            d0[j] = h ? hi : lo;
        }
        uint4v v0 = {d0[0], d0[1], d0[2], d0[3]};
        qf = __builtin_bit_cast(short8, v0);
    }

    // ---------------- attention loop (32 keys/iter over all 1024) ----------
    f32x16 zf16 = {};
    f32x16 D0 = {};
    float rs0 = 0.f;

    const unsigned short* Kp   = Ksh + (size_t)q31 * 16 + h * 8;  // A: K[key][8h+j]
    const unsigned short* Vrow = Vsh + (size_t)(q31 & 15) * VSTR; // B: V^T row d

    short8 kf = *(const short8*)Kp;

    for (int kb = 0; kb < Nn; kb += 32) {
        short8 kfn = *(const short8*)(Kp + (size_t)((kb + 32) & (Nn - 1)) * 16);

        f32x16 s0 = __builtin_amdgcn_mfma_f32_32x32x16_bf16(kf, qf, zf16, 0, 0, 0);
        kf = kfn;

        // ---- half A: S regs 0..7 = keys {4h+0..3, 8+4h+0..3} of kb..kb+15 --
        {
            unsigned pa[4];
#pragma unroll
            for (int g = 0; g < 2; g++) {
                float e0 = EXP2(s0[4*g+0]), e1 = EXP2(s0[4*g+1]);
                float e2 = EXP2(s0[4*g+2]), e3 = EXP2(s0[4*g+3]);
                rs0 += (e0 + e1) + (e2 + e3);
                pa[2*g]   = pack2bf(e0, e1);
                pa[2*g+1] = pack2bf(e2, e3);
            }
            const unsigned short* vb = Vrow + kb + 4*h;
            uint2 va = *(const uint2*)vb;
            uint2 vc = *(const uint2*)(vb + 8);
            uint4v vv = {va.x, va.y, vc.x, vc.y};
            uint4v a0 = {pa[0], pa[1], pa[2], pa[3]};
            D0 = __builtin_amdgcn_mfma_f32_32x32x16_bf16(
                     __builtin_bit_cast(short8, a0),
                     __builtin_bit_cast(short8, vv), D0, 0, 0, 0);
        }
        // ---- half B: S regs 8..15 = keys {16+4h+0..3, 24+4h+0..3} ----------
        {
            unsigned pb[4];
#pragma unroll
            for (int g = 2; g < 4; g++) {
                float e0 = EXP2(s0[4*g+0]), e1 = EXP2(s0[4*g+1]);
                float e2 = EXP2(s0[4*g+2]), e3 = EXP2(s0[4*g+3]);
                rs0 += (e0 + e1) + (e2 + e3);
                pb[2*(g-2)]   = pack2bf(e0, e1);
                pb[2*(g-2)+1] = pack2bf(e2, e3);
            }
            const unsigned short* vb = Vrow + kb + 16 + 4*h;
            uint2 va = *(const uint2*)vb;
            uint2 vc = *(const uint2*)(vb + 8);
            uint4v vv = {va.x, va.y, vc.x, vc.y};
            uint4v a0 = {pb[0], pb[1], pb[2], pb[3]};
            D0 = __builtin_amdgcn_mfma_f32_32x32x16_bf16(
                     __builtin_bit_cast(short8, a0),
                     __builtin_bit_cast(short8, vv), D0, 0, 0, 0);
        }
    }

    rs0 += __shfl_xor(rs0, 32);

    __syncthreads();   // all waves done with K reads before O overlays it

    // ---- stage O (C-layout -> row-major [q_local][16]) + rs ----
    float* Ow = (float*)smem;                        // 512 q x 16 f32
    if (q31 < 16) {
#pragma unroll
        for (int r = 0; r < 16; r++) {
            int m = (r & 3) + 8 * (r >> 2) + 4 * h;  // query within wave's 32
            Ow[(wid * 32 + m) * 16 + q31] = D0[r];
        }
    }
    float* Rw = (float*)(smem + RS_OFF);
    if (h == 0) Rw[wid * 32 + q31] = rs0;
    __syncthreads();

    // ---------------- epilogue: thread t<512 handles query qbase+t ----------
    if (t < 512) {
        const int n = qbase + t;
        float xr[16]; load_row16(Xb + (size_t)n * Dd, xr);
        float q[16];  project(xr, wq, bql, i, q);
        const float* orow = Ow + t * 16;
        const float  inv  = 1.f / Rw[t];

        float a[16];
#pragma unroll
        for (int c = 0; c < 16; c++) a[c] = q[c] + orow[c] * inv;

        float tt[16];
#pragma unroll
        for (int r = 0; r < 16; r++) {
            float acc = bol[r];
#pragma unroll
            for (int c = 0; c < 16; c++) acc = fmaf(a[c], wo[r * 16 + c], acc);
            tt[r] = fmaxf(acc, 0.f);
        }
#pragma unroll
        for (int r = 0; r < 16; r++) a[r] += (r < i) ? tt[r] : 0.f;

        float mu = bfl[0], al = bfl[1];
#pragma unroll
        for (int c = 0; c < 16; c++) {
            mu = fmaf(a[c], wf[c], mu);
            al = fmaf(a[c], wf[16 + c], al);
        }
        out[((size_t)(b * Nn + n)) * Dd + i] = (xr[i] - mu) * __expf(-al);
        als[(size_t)l * (Bb * Nn) + b * Nn + n] = al;
    }
}

// ---------------------------------------------------------------------------
// Final: layer-0 Z + logdet = -(alpha0 + sum_l al)
// ---------------------------------------------------------------------------
__launch_bounds__(256)
__global__ void gf_final(const float* __restrict__ X, const float* __restrict__ ip,
                         const float* __restrict__ als, float* __restrict__ out) {
    const int idx = blockIdx.x * 256 + threadIdx.x;      // 0..Bb*Nn-1
    const float mu = ip[0], a0 = ip[1];
    float x0 = X[(size_t)idx * Dd];
    out[(size_t)idx * Dd] = (x0 - mu) * __expf(-a0);
    float ld = -a0;
#pragma unroll
    for (int l = 0; l < NL; l++) ld -= als[(size_t)l * (Bb * Nn) + idx];
    out[(size_t)Bb * Nn * Dd + idx] = ld;
}

// ---------------------------------------------------------------------------
// Fallback path (R1): init + fp32 kernel, if big dynamic LDS / ws unavailable
// ---------------------------------------------------------------------------
__global__ void gf_init(const float* __restrict__ X, const float* __restrict__ ip,
                        float* __restrict__ out) {
    int idx = blockIdx.x * blockDim.x + threadIdx.x;
    if (idx >= Bb * Nn) return;
    float mu = ip[0], alpha = ip[1];
    float x0 = X[(size_t)idx * Dd];
    out[(size_t)idx * Dd] = (x0 - mu) * __expf(-alpha);
    out[(size_t)Bb * Nn * Dd + idx] = -alpha;
}

__launch_bounds__(512, 2)
__global__ void gf_layer_fb(const float* __restrict__ X,
                            const float* __restrict__ Wq, const float* __restrict__ bq,
                            const float* __restrict__ Wk, const float* __restrict__ bk,
                            const float* __restrict__ Wv, const float* __restrict__ bv,
                            const float* __restrict__ Wo, const float* __restrict__ bo,
                            const float* __restrict__ Wf, const float* __restrict__ bf,
                            float* __restrict__ out) {
    const int l = blockIdx.x, b = blockIdx.y, i = l + 1, t = threadIdx.x;
    const float rscale = rsqrtf((float)i);
    __shared__ float Ksh[512 * 16];
    __shared__ float Vsh[512 * 16];
    const float* Xb = X + (size_t)b * Nn * Dd;
    const float* wq = Wq + l * 256; const float* wk = Wk + l * 256;
    const float* wv = Wv + l * 256; const float* wo = Wo + l * 256;
    const float* wf = Wf + l * 32;
    const float* bql = bq + l * 16; const float* bkl = bk + l * 16;
    const float* bvl = bv + l * 16; const float* bol = bo + l * 16;
    const float* bfl = bf + l * 2;
    const int n0 = t, n1 = t + 512;
    float q0[16], q1[16], xi0, xi1;
    {
        float xr[16];
        load_row16(Xb + (size_t)n0 * Dd, xr); xi0 = xr[i]; project(xr, wq, bql, i, q0);
        load_row16(Xb + (size_t)n1 * Dd, xr); xi1 = xr[i]; project(xr, wq, bql, i, q1);
    }
    float o0[16], o1[16];
#pragma unroll
    for (int c = 0; c < 16; c++) { o0[c] = 0.f; o1[c] = 0.f; }
    float ls0 = 0.f, ls1 = 0.f;
    for (int ch = 0; ch < 2; ch++) {
        float kr[16], vr[16];
        {
            float kx[16];
            load_row16(Xb + (size_t)(ch * 512 + t) * Dd, kx);
            project(kx, wk, bkl, i, kr);
            project(kx, wv, bvl, i, vr);
        }
        __syncthreads();
#pragma unroll
        for (int j = 0; j < 4; j++) {
            ((float4*)&Ksh[t * 16])[j] = ((float4*)kr)[j];
            ((float4*)&Vsh[t * 16])[j] = ((float4*)vr)[j];
        }
        __syncthreads();
        for (int k = 0; k < 512; k++) {
            float kk[16], vv[16];
#pragma unroll
            for (int j = 0; j < 4; j++) ((float4*)kk)[j] = ((const float4*)&Ksh[k * 16])[j];
            float s0 = 0.f, s1 = 0.f;
#pragma unroll
            for (int c = 0; c < 16; c++) { s0 = fmaf(q0[c], kk[c], s0); s1 = fmaf(q1[c], kk[c], s1); }
            float p0 = __expf(s0 * rscale), p1 = __expf(s1 * rscale);
            ls0 += p0; ls1 += p1;
#pragma unroll
            for (int j = 0; j < 4; j++) ((float4*)vv)[j] = ((const float4*)&Vsh[k * 16])[j];
#pragma unroll
            for (int c = 0; c < 16; c++) { o0[c] = fmaf(p0, vv[c], o0[c]); o1[c] = fmaf(p1, vv[c], o1[c]); }
        }
        __syncthreads();
    }
    float* logdet = out + (size_t)Bb * Nn * Dd;
#pragma unroll
    for (int rowsel = 0; rowsel < 2; rowsel++) {
        const float* qr = rowsel ? q1 : q0; const float* orr = rowsel ? o1 : o0;
        float lsum = rowsel ? ls1 : ls0; float xin = rowsel ? xi1 : xi0;
        int n = rowsel ? n1 : n0;
        float a[16]; float inv = 1.f / lsum;
#pragma unroll
        for (int c = 0; c < 16; c++) a[c] = qr[c] + orr[c] * inv;
        float tt[16];
#pragma unroll
        for (int r = 0; r < 16; r++) {
            float acc = bol[r];
#pragma unroll
            for (int c = 0; c < 16; c++) acc = fmaf(a[c], wo[r * 16 + c], acc);
            tt[r] = fmaxf(acc, 0.f);
        }
#pragma unroll
        for (int r = 0; r < 16; r++) a[r] += (r < i) ? tt[r] : 0.f;
        float mu = bfl[0], al = bfl[1];
#pragma unroll
        for (int c = 0; c < 16; c++) { mu = fmaf(a[c], wf[c], mu); al = fmaf(a[c], wf[16 + c], al); }
        out[((size_t)(b * Nn + n)) * Dd + i] = (xin - mu) * __expf(-al);
        atomicAdd(logdet + b * Nn + n, -al);
    }
}

extern "C" void kernel_launch(void* const* d_in, const int* in_sizes, int n_in,
                              void* d_out, int out_size, void* d_ws, size_t ws_size,
                              hipStream_t stream) {
    const float* X  = (const float*)d_in[0];
    const float* ip = (const float*)d_in[1];
    const float* Wq = (const float*)d_in[2];
    const float* bq = (const float*)d_in[3];
    const float* Wk = (const float*)d_in[4];
    const float* bk = (const float*)d_in[5];
    const float* Wv = (const float*)d_in[6];
    const float* bv = (const float*)d_in[7];
    const float* Wo = (const float*)d_in[8];
    const float* bo = (const float*)d_in[9];
    const float* Wf = (const float*)d_in[10];
    const float* bf = (const float*)d_in[11];
    float* out = (float*)d_out;

    const size_t need = (size_t)NL * Bb * Nn * sizeof(float);   // 983 KB for als
    hipError_t e = hipFuncSetAttribute((const void*)gf_fused,
                                       hipFuncAttributeMaxDynamicSharedMemorySize,
                                       LDS_TOTAL);
    if (e == hipSuccess && ws_size >= need) {
        float* als = (float*)d_ws;
        gf_fused<<<dim3(NL, Bb, 2), 1024, LDS_TOTAL, stream>>>(
            X, Wq, bq, Wk, bk, Wv, bv, Wo, bo, Wf, bf, als, out);
        gf_final<<<Bb * Nn / 256, 256, 0, stream>>>(X, ip, als, out);
    } else {
        gf_init<<<(Bb * Nn + 255) / 256, 256, 0, stream>>>(X, ip, out);
        gf_layer_fb<<<dim3(NL, Bb), 512, 0, stream>>>(
            X, Wq, bq, Wk, bk, Wv, bv, Wo, bo, Wf, bf, out);
    }
}